// Round 1
// baseline (889.467 us; speedup 1.0000x reference)
//
#include <hip/hip_runtime.h>

// QuantizedLinear: out[m][n] = 0.01 * sum_k x[m][k]*(q[n][k]-8) + (0.01*0.047)*qbias[n]
// M=16384 (8*2048), N=4096, K=4096. Compute-bound bf16 MFMA GEMM (gemm_bt).

typedef __bf16 bf16x8 __attribute__((ext_vector_type(8)));
typedef float f32x4 __attribute__((ext_vector_type(4)));
typedef unsigned short u16;
typedef u16 u16x4 __attribute__((ext_vector_type(4)));
typedef u16 u16x8 __attribute__((ext_vector_type(8)));

static constexpr int Kdim = 4096;
static constexpr int Ndim = 4096;
static constexpr int BM = 128, BN = 128, BK = 64;

__device__ __forceinline__ u16 f2bf(float f) {
  union { float f; unsigned u; } c; c.f = f;
  unsigned u = c.u;
  return (u16)((u + 0x7FFFu + ((u >> 16) & 1u)) >> 16);  // RNE
}

// ---- pre-pass 1: x fp32 -> bf16 (memory-bound, ~60us) ----
__global__ __launch_bounds__(256) void cvt_x_kernel(const float* __restrict__ x,
                                                    u16* __restrict__ xb, int n4) {
  int stride = gridDim.x * blockDim.x;
  for (int i = blockIdx.x * blockDim.x + threadIdx.x; i < n4; i += stride) {
    float4 v = reinterpret_cast<const float4*>(x)[i];
    u16x4 o;
    o.x = f2bf(v.x); o.y = f2bf(v.y); o.z = f2bf(v.z); o.w = f2bf(v.w);
    reinterpret_cast<u16x4*>(xb)[i] = o;
  }
}

// ---- pre-pass 2: packed nibbles -> bf16 integer weights (q-8), exact ----
__global__ __launch_bounds__(256) void dequant_w_kernel(const int* __restrict__ pw,
                                                        u16* __restrict__ wb, int n4) {
  int stride = gridDim.x * blockDim.x;
  for (int i = blockIdx.x * blockDim.x + threadIdx.x; i < n4; i += stride) {
    int4 v = reinterpret_cast<const int4*>(pw)[i];
    int a[4] = {v.x, v.y, v.z, v.w};
    u16x8 o;
#pragma unroll
    for (int j = 0; j < 4; ++j) {
      o[2 * j]     = f2bf((float)((a[j] & 15) - 8));        // low nibble -> even col
      o[2 * j + 1] = f2bf((float)(((a[j] >> 4) & 15) - 8)); // high nibble -> odd col
    }
    // out offset = 2 * input flat offset -> contiguous 16B store
    reinterpret_cast<u16x8*>(wb)[i] = o;
  }
}

// ---- async global->LDS, 16B per lane, wave-uniform LDS base ----
__device__ __forceinline__ void gload_lds16(const u16* g, u16* l) {
  __builtin_amdgcn_global_load_lds(
      (const __attribute__((address_space(1))) void*)g,
      (__attribute__((address_space(3))) void*)l,
      16, 0, 0);
}

// ---- main GEMM: C[M][N] = A[M][K](bf16) * B[N][K](bf16)^T, m97 structure ----
__global__ __launch_bounds__(256) void gemm_kernel(const u16* __restrict__ A,
                                                   const u16* __restrict__ B,
                                                   const int* __restrict__ qbias,
                                                   float* __restrict__ C) {
  __shared__ u16 As[BM * BK];  // [128][64] row-major, linear (global_load_lds dest)
  __shared__ u16 Bs[BN * BK];

  const int tid = threadIdx.x;
  const int wave = tid >> 6, lane = tid & 63;
  const int wm = wave >> 1, wn = wave & 1;  // 2x2 waves, each owns 64x64
  const int m0 = blockIdx.y * BM, n0 = blockIdx.x * BN;

  // staging: thread t loads 16B: row = i*32 + t/8, col = (t%8)*8 of the tile
  const u16* ga = A + (size_t)(m0 + tid / 8) * Kdim + (tid % 8) * 8;
  const u16* gb = B + (size_t)(n0 + tid / 8) * Kdim + (tid % 8) * 8;
  u16* la = As + wave * 512;  // wave-uniform base; HW adds lane*16B
  u16* lb = Bs + wave * 512;

  f32x4 acc[4][4] = {};

  for (int k0 = 0; k0 < Kdim; k0 += BK) {
#pragma unroll
    for (int i = 0; i < 4; ++i) {
      gload_lds16(ga + (size_t)i * 32 * Kdim, la + i * 2048);
      gload_lds16(gb + (size_t)i * 32 * Kdim, lb + i * 2048);
    }
    ga += BK; gb += BK;
    asm volatile("s_waitcnt vmcnt(0)" ::: "memory");
    __syncthreads();

    const int row = lane & 15;
#pragma unroll
    for (int kk = 0; kk < 2; ++kk) {
      const int kof = kk * 32 + (lane >> 4) * 8;
      bf16x8 af[4], bf[4];
#pragma unroll
      for (int m = 0; m < 4; ++m)
        af[m] = *(const bf16x8*)&As[(wm * 64 + m * 16 + row) * BK + kof];
#pragma unroll
      for (int n = 0; n < 4; ++n)
        bf[n] = *(const bf16x8*)&Bs[(wn * 64 + n * 16 + row) * BK + kof];
#pragma unroll
      for (int m = 0; m < 4; ++m)
#pragma unroll
        for (int n = 0; n < 4; ++n)
          acc[m][n] = __builtin_amdgcn_mfma_f32_16x16x32_bf16(af[m], bf[n], acc[m][n], 0, 0, 0);
    }
    __syncthreads();
  }

  // epilogue: C/D layout col=lane&15, row=(lane>>4)*4+j  [m89-verified]
  const float wscale = 0.01f;
  const float bscale = (float)(0.01 * 0.047);
  const int col_base = n0 + wn * 64 + (lane & 15);
  const int row_base = m0 + wm * 64 + ((lane >> 4) << 2);
#pragma unroll
  for (int n = 0; n < 4; ++n) {
    const int col = col_base + n * 16;
    const float bias = bscale * (float)qbias[col];
#pragma unroll
    for (int m = 0; m < 4; ++m) {
      const int r0 = row_base + m * 16;
#pragma unroll
      for (int j = 0; j < 4; ++j)
        C[(size_t)(r0 + j) * Ndim + col] = wscale * acc[m][n][j] + bias;
    }
  }
}

extern "C" void kernel_launch(void* const* d_in, const int* in_sizes, int n_in,
                              void* d_out, int out_size, void* d_ws, size_t ws_size,
                              hipStream_t stream) {
  const float* x  = (const float*)d_in[0];
  const int*   pw = (const int*)d_in[1];
  const int*   qb = (const int*)d_in[2];
  float* out = (float*)d_out;

  const int M = in_sizes[0] / Kdim;  // 16384

  u16* xb = (u16*)d_ws;                                        // M*K bf16 = 134MB
  u16* wb = (u16*)((char*)d_ws + (size_t)M * Kdim * 2);        // N*K bf16 = 33.5MB

  cvt_x_kernel<<<2048, 256, 0, stream>>>(x, xb, M * Kdim / 4);
  dequant_w_kernel<<<1024, 256, 0, stream>>>(pw, wb, Ndim * Kdim / 8);

  dim3 grid(Ndim / BN, M / BM);
  gemm_kernel<<<grid, 256, 0, stream>>>(xb, wb, qb, out);
}

// Round 2
// 640.276 us; speedup vs baseline: 1.3892x; 1.3892x over previous
//
#include <hip/hip_runtime.h>

// QuantizedLinear: out[m][n] = 0.01 * sum_k x[m][k]*(q[n][k]-8) + (0.01*0.047)*qbias[n]
// M=16384, N=4096, K=4096. 256x256-tile 8-wave GEMM, 2-phase/K-tile(BK=32),
// 4-deep LDS pipeline with counted vmcnt (T3+T4), both-sides XOR swizzle (T2),
// setprio around MFMA clusters (T5), XCD-aware block swizzle (T1).

typedef __bf16 bf16x8 __attribute__((ext_vector_type(8)));
typedef float f32x4 __attribute__((ext_vector_type(4)));
typedef unsigned short u16;
typedef u16 u16x4 __attribute__((ext_vector_type(4)));
typedef u16 u16x8 __attribute__((ext_vector_type(8)));

static constexpr int Kdim = 4096;
static constexpr int Ndim = 4096;
static constexpr int BM = 256, BN = 256, BK = 32;
static constexpr int NKT = Kdim / BK;        // 128 K-tiles
static constexpr int BUFH = BM * BK;         // 8192 halfwords per buffer per matrix

__device__ __forceinline__ u16 f2bf(float f) {
  union { float f; unsigned u; } c; c.f = f;
  unsigned u = c.u;
  return (u16)((u + 0x7FFFu + ((u >> 16) & 1u)) >> 16);  // RNE
}

// ---- pre-pass 1: x fp32 -> bf16 ----
__global__ __launch_bounds__(256) void cvt_x_kernel(const float* __restrict__ x,
                                                    u16* __restrict__ xb, int n4) {
  int stride = gridDim.x * blockDim.x;
  for (int i = blockIdx.x * blockDim.x + threadIdx.x; i < n4; i += stride) {
    float4 v = reinterpret_cast<const float4*>(x)[i];
    u16x4 o;
    o.x = f2bf(v.x); o.y = f2bf(v.y); o.z = f2bf(v.z); o.w = f2bf(v.w);
    reinterpret_cast<u16x4*>(xb)[i] = o;
  }
}

// ---- pre-pass 2: packed nibbles -> bf16 integer weights (q-8), exact ----
__global__ __launch_bounds__(256) void dequant_w_kernel(const int* __restrict__ pw,
                                                        u16* __restrict__ wb, int n4) {
  int stride = gridDim.x * blockDim.x;
  for (int i = blockIdx.x * blockDim.x + threadIdx.x; i < n4; i += stride) {
    int4 v = reinterpret_cast<const int4*>(pw)[i];
    int a[4] = {v.x, v.y, v.z, v.w};
    u16x8 o;
#pragma unroll
    for (int j = 0; j < 4; ++j) {
      o[2 * j]     = f2bf((float)((a[j] & 15) - 8));
      o[2 * j + 1] = f2bf((float)(((a[j] >> 4) & 15) - 8));
    }
    reinterpret_cast<u16x8*>(wb)[i] = o;
  }
}

__device__ __forceinline__ void gload16(const u16* g, const u16* l) {
  __builtin_amdgcn_global_load_lds(
      (const __attribute__((address_space(1))) void*)g,
      (__attribute__((address_space(3))) void*)l,
      16, 0, 0);
}

// ---- main GEMM ----
__global__ __launch_bounds__(512, 2) void gemm_kernel(const u16* __restrict__ A,
                                                      const u16* __restrict__ B,
                                                      const int* __restrict__ qbias,
                                                      float* __restrict__ C,
                                                      int Mtiles) {
  extern __shared__ u16 smem[];
  u16* As = smem;                 // [4][256*32] halfwords = 64 KiB
  u16* Bs = smem + 4 * BUFH;      // [4][256*32]           = 64 KiB

  const int tid = threadIdx.x;
  const int wave = tid >> 6, lane = tid & 63;
  const int wm = wave >> 2, wn = wave & 3;   // 2 (M) x 4 (N) waves

  // T1: XCD-aware chunked swizzle (grid = Mtiles*16, multiple of 8)
  const int nwg = gridDim.x;
  const int cpx = nwg >> 3;
  const int bid = blockIdx.x;
  const int swz = (bid & 7) * cpx + (bid >> 3);
  const int by = swz % Mtiles;               // M tile (fast within XCD chunk -> shared B panel in L2)
  const int bx = swz / Mtiles;               // N tile
  const int m0 = by * BM, n0 = bx * BN;

  // staging geometry: chunk c = round*512 + tid; row = c>>2; 16B slot xor-swizzled by row&3
  const int c0 = tid, c1 = 512 + tid;
  const int r0 = c0 >> 2, r1 = c1 >> 2;
  const int f0 = ((c0 & 3) ^ (r0 & 3)) << 3;   // halfword col within 32-col row
  const int f1 = ((c1 & 3) ^ (r1 & 3)) << 3;
  const u16* pa0 = A + (size_t)(m0 + r0) * Kdim + f0;
  const u16* pa1 = A + (size_t)(m0 + r1) * Kdim + f1;
  const u16* pb0 = B + (size_t)(n0 + r0) * Kdim + f0;
  const u16* pb1 = B + (size_t)(n0 + r1) * Kdim + f1;
  const int ldsc0 = (0 * 512 + (tid & 0x1C0)) * 8;   // wave-uniform LDS halfword offsets
  const int ldsc1 = (1 * 512 + (tid & 0x1C0)) * 8;

  // ds_read geometry (same XOR involution as the staged source permutation)
  const int rA = wm * 128 + (lane & 15);
  const int rB = wn * 64 + (lane & 15);
  const int kof = ((lane >> 4) ^ (lane & 3)) << 3;   // halfwords

  f32x4 acc[8][4] = {};

  // prologue: stage K-tiles 0,1,2 into buffers 0,1,2 (12 loads/thread)
#pragma unroll
  for (int tt = 0; tt < 3; ++tt) {
    const int ko = tt * BK;
    const u16* la = As + tt * BUFH;
    const u16* lb = Bs + tt * BUFH;
    gload16(pa0 + ko, la + ldsc0);
    gload16(pa1 + ko, la + ldsc1);
    gload16(pb0 + ko, lb + ldsc0);
    gload16(pb1 + ko, lb + ldsc1);
  }
  asm volatile("s_waitcnt vmcnt(8)" ::: "memory");   // tile 0 landed; tiles 1,2 in flight
  __builtin_amdgcn_s_barrier();

  for (int t = 0; t < NKT; ++t) {
    const u16* a_lds = As + (t & 3) * BUFH;
    const u16* b_lds = Bs + (t & 3) * BUFH;
    const u16* a_wr = As + ((t + 3) & 3) * BUFH;
    const u16* b_wr = Bs + ((t + 3) & 3) * BUFH;
    const bool st = (t + 3) < NKT;
    const int ko = (t + 3) * BK;

    // ---------- phase A: m-frags 0..3 ----------
    bf16x8 alo[4], bfr[4];
#pragma unroll
    for (int m = 0; m < 4; ++m)
      alo[m] = *(const bf16x8*)(a_lds + (rA + m * 16) * BK + kof);
#pragma unroll
    for (int n = 0; n < 4; ++n)
      bfr[n] = *(const bf16x8*)(b_lds + (rB + n * 16) * BK + kof);
    if (st) { gload16(pa0 + ko, a_wr + ldsc0); gload16(pa1 + ko, a_wr + ldsc1); }
    __builtin_amdgcn_s_barrier();
    asm volatile("s_waitcnt lgkmcnt(0)" ::: "memory");
    __builtin_amdgcn_sched_barrier(0);
    __builtin_amdgcn_s_setprio(1);
#pragma unroll
    for (int m = 0; m < 4; ++m)
#pragma unroll
      for (int n = 0; n < 4; ++n)
        acc[m][n] = __builtin_amdgcn_mfma_f32_16x16x32_bf16(alo[m], bfr[n], acc[m][n], 0, 0, 0);
    __builtin_amdgcn_s_setprio(0);
    __builtin_amdgcn_sched_barrier(0);
    __builtin_amdgcn_s_barrier();

    // ---------- phase B: m-frags 4..7 (reuse bfr) ----------
    bf16x8 ahi[4];
#pragma unroll
    for (int m = 0; m < 4; ++m)
      ahi[m] = *(const bf16x8*)(a_lds + (rA + 64 + m * 16) * BK + kof);
    if (st) { gload16(pb0 + ko, b_wr + ldsc0); gload16(pb1 + ko, b_wr + ldsc1); }
    __builtin_amdgcn_s_barrier();
    asm volatile("s_waitcnt lgkmcnt(0)" ::: "memory");
    __builtin_amdgcn_sched_barrier(0);
    __builtin_amdgcn_s_setprio(1);
#pragma unroll
    for (int m = 0; m < 4; ++m)
#pragma unroll
      for (int n = 0; n < 4; ++n)
        acc[m + 4][n] = __builtin_amdgcn_mfma_f32_16x16x32_bf16(ahi[m], bfr[n], acc[m + 4][n], 0, 0, 0);
    __builtin_amdgcn_s_setprio(0);
    __builtin_amdgcn_sched_barrier(0);

    // counted vmcnt: tile t+1 must be landed; keep t+2, t+3 in flight (never 0 mid-loop)
    if (t + 3 < NKT)      asm volatile("s_waitcnt vmcnt(8)" ::: "memory");
    else if (t + 2 < NKT) asm volatile("s_waitcnt vmcnt(4)" ::: "memory");
    else if (t + 1 < NKT) asm volatile("s_waitcnt vmcnt(0)" ::: "memory");
    __builtin_amdgcn_s_barrier();
  }

  // epilogue: C/D layout col=lane&15, row=(lane>>4)*4+j
  const float wscale = 0.01f;
  const float bscale = (float)(0.01 * 0.047);
  const int col0 = n0 + wn * 64 + (lane & 15);
  const int row0 = m0 + wm * 128 + ((lane >> 4) << 2);
#pragma unroll
  for (int n = 0; n < 4; ++n) {
    const int col = col0 + n * 16;
    const float bias = bscale * (float)qbias[col];
#pragma unroll
    for (int m = 0; m < 8; ++m) {
      const int rr = row0 + m * 16;
#pragma unroll
      for (int j = 0; j < 4; ++j)
        C[(size_t)(rr + j) * Ndim + col] = wscale * acc[m][n][j] + bias;
    }
  }
}

extern "C" void kernel_launch(void* const* d_in, const int* in_sizes, int n_in,
                              void* d_out, int out_size, void* d_ws, size_t ws_size,
                              hipStream_t stream) {
  const float* x  = (const float*)d_in[0];
  const int*   pw = (const int*)d_in[1];
  const int*   qb = (const int*)d_in[2];
  float* out = (float*)d_out;

  const int M = in_sizes[0] / Kdim;  // 16384

  u16* xb = (u16*)d_ws;                                  // M*K bf16
  u16* wb = (u16*)((char*)d_ws + (size_t)M * Kdim * 2);  // N*K bf16

  cvt_x_kernel<<<2048, 256, 0, stream>>>(x, xb, M * Kdim / 4);
  dequant_w_kernel<<<1024, 256, 0, stream>>>(pw, wb, Ndim * Kdim / 8);

  const int Mtiles = M / BM;                 // 64
  const int nwg = Mtiles * (Ndim / BN);      // 1024, multiple of 8
  static const size_t lds_bytes = 2u * 4u * BUFH * sizeof(u16);  // 128 KiB
  (void)hipFuncSetAttribute((const void*)gemm_kernel,
                            hipFuncAttributeMaxDynamicSharedMemorySize,
                            (int)lds_bytes);
  gemm_kernel<<<nwg, 512, lds_bytes, stream>>>(xb, wb, qb, out, Mtiles);
}